// Round 7
// baseline (242.897 us; speedup 1.0000x reference)
//
#include <hip/hip_runtime.h>
#include <hip/hip_bf16.h>

#define LEAKY 0.2f
#define BINB 8          // 256 nodes per bin (requires N <= 65536 for u16 packing)
#define TILE 2048       // edges per block in binning kernels (391 blocks: parallelism)
#define CAP 8192        // LDS bucket-segment capacity per bin (avg ~4081)

static inline int ceil_div(int a, int b) { return (a + b - 1) / b; }

typedef __bf16 bf16x8 __attribute__((ext_vector_type(8)));
typedef float f32x4 __attribute__((ext_vector_type(4)));

// f32 -> bf16 bits, round-to-nearest-even
__device__ __forceinline__ ushort f2bf(float f) {
    unsigned int x = __float_as_uint(f);
    unsigned int r = (x + 0x7fffu + ((x >> 16) & 1u)) >> 16;
    return (ushort)r;
}

// ---------------- CSR build (two-level, coalesced writes) ----------------
// Round-4 lesson: one-pass random 4B scatter = 17x HBM write amplification.

__global__ __launch_bounds__(256) void bin_count(const int* __restrict__ dst,
                                                 int* __restrict__ bin_cnt, int E, int NB) {
    __shared__ int h[256];
    int t = threadIdx.x;
    h[t] = 0;
    __syncthreads();
    int base = blockIdx.x * TILE;
#pragma unroll
    for (int j = 0; j < TILE / 256; ++j) {
        int i = base + j * 256 + t;
        if (i < E) atomicAdd(&h[dst[i] >> BINB], 1);
    }
    __syncthreads();
    if (t < NB && h[t]) atomicAdd(&bin_cnt[t], h[t]);
}

__global__ __launch_bounds__(256) void bin_scan(const int* __restrict__ bin_cnt,
                                                int* __restrict__ binStart,
                                                int* __restrict__ bin_cursor,
                                                int* __restrict__ rowstart,
                                                int NB, int N, int E) {
    __shared__ int s[256];
    int t = threadIdx.x;
    int v = (t < NB) ? bin_cnt[t] : 0;
    s[t] = v;
    __syncthreads();
    for (int off = 1; off < 256; off <<= 1) {
        int x = (t >= off) ? s[t - off] : 0;
        __syncthreads();
        s[t] += x;
        __syncthreads();
    }
    int excl = s[t] - v;
    if (t < NB) {
        binStart[t] = excl;
        bin_cursor[t] = excl;
        if (t == NB - 1) binStart[NB] = excl + v;
    }
    if (t == 0) rowstart[N] = E;
}

__global__ __launch_bounds__(256) void bin_scatter(const int* __restrict__ src,
                                                   const int* __restrict__ dst,
                                                   int* __restrict__ bin_cursor,
                                                   unsigned int* __restrict__ coarse, int E) {
    __shared__ int hist[256], scn[256], gbase[256], lcur[256];
    __shared__ unsigned int outp[TILE];
    __shared__ int gidx[TILE];
    int t = threadIdx.x;
    hist[t] = 0;
    __syncthreads();
    int base = blockIdx.x * TILE;
    int dloc[TILE / 256];
#pragma unroll
    for (int j = 0; j < TILE / 256; ++j) {
        int i = base + j * 256 + t;
        int d = (i < E) ? dst[i] : -1;
        dloc[j] = d;
        if (d >= 0) atomicAdd(&hist[d >> BINB], 1);
    }
    __syncthreads();
    int hv = hist[t];
    scn[t] = hv;
    __syncthreads();
    for (int off = 1; off < 256; off <<= 1) {
        int x = (t >= off) ? scn[t - off] : 0;
        __syncthreads();
        scn[t] += x;
        __syncthreads();
    }
    int excl = scn[t] - hv;
    if (hv > 0) gbase[t] = atomicAdd(&bin_cursor[t], hv);
    lcur[t] = excl;
    scn[t] = excl;
    __syncthreads();
#pragma unroll
    for (int j = 0; j < TILE / 256; ++j) {
        int i = base + j * 256 + t;
        int d = dloc[j];
        if (d >= 0) {
            int b = d >> BINB;
            int pos = atomicAdd(&lcur[b], 1);
            outp[pos] = (unsigned int)src[i] | ((unsigned int)(d & ((1 << BINB) - 1)) << 16);
            gidx[pos] = gbase[b] + (pos - scn[b]);
        }
    }
    __syncthreads();
    int cnt = min(TILE, E - base);
    for (int j = t; j < cnt; j += 256) coarse[gidx[j]] = outp[j];
}

__global__ __launch_bounds__(256) void fine_csr(const unsigned int* __restrict__ coarse,
                                                const int* __restrict__ binStart,
                                                int* __restrict__ rowstart,
                                                ushort* __restrict__ bucket, int N) {
    __shared__ int hist[256], scn[256], cur[256];
    __shared__ ushort sb[CAP];
    int b = blockIdx.x, t = threadIdx.x;
    int e0 = binStart[b], e1 = binStart[b + 1];
    int cnt = e1 - e0;
    hist[t] = 0;
    __syncthreads();
    for (int j = e0 + t; j < e1; j += 256) atomicAdd(&hist[coarse[j] >> 16], 1);
    __syncthreads();
    int hv = hist[t];
    scn[t] = hv;
    __syncthreads();
    for (int off = 1; off < 256; off <<= 1) {
        int x = (t >= off) ? scn[t - off] : 0;
        __syncthreads();
        scn[t] += x;
        __syncthreads();
    }
    int excl = scn[t] - hv;
    int n = (b << BINB) + t;
    if (n < N) rowstart[n] = e0 + excl;
    cur[t] = excl;
    __syncthreads();
    bool fit = (cnt <= CAP);
    for (int j = e0 + t; j < e1; j += 256) {
        unsigned int p = coarse[j];
        int dl = p >> 16;
        int pos = atomicAdd(&cur[dl], 1);
        ushort sv = (ushort)(p & 0xffffu);
        if (fit) sb[pos] = sv;
        else bucket[e0 + pos] = sv;
    }
    __syncthreads();
    if (fit)
        for (int j = t; j < cnt; j += 256) bucket[e0 + j] = sb[j];
}

// ---------------- W convert: Wt[n][k] = bf16(W[k][n]) ----------------
__global__ __launch_bounds__(256) void convert_w(const float* __restrict__ W1,
                                                 const float* __restrict__ W2,
                                                 ushort* __restrict__ Wt1,
                                                 ushort* __restrict__ Wt2) {
    int idx = blockIdx.x * 256 + threadIdx.x;
    const float* W = (idx < 16384) ? W1 : W2;
    ushort* O = (idx < 16384) ? Wt1 : Wt2;
    int i = idx & 16383;
    int k = i >> 7, n = i & 127;
    O[n * 128 + k] = f2bf(W[i]);
}

// ---------------- MFMA GEMM + attention coefficients ----------------
// Block 64x128, 4 waves (2M x 2N). Input either f32 (layer 1) or bf16 (layer 2).
#define LDK 136
template <bool BF16IN>
__global__ __launch_bounds__(256) void gemm_attn_mfma(const void* __restrict__ in_,
                                                      const ushort* __restrict__ Wt,
                                                      const float* __restrict__ al,
                                                      const float* __restrict__ ar,
                                                      ushort* __restrict__ feat,
                                                      float* __restrict__ el,
                                                      float* __restrict__ er, int N) {
    __shared__ ushort sA[64 * LDK];
    int tid = threadIdx.x;
    int rowbase = blockIdx.x * 64;

    if (BF16IN) {
        const ushort* in = (const ushort*)in_;
#pragma unroll
        for (int i = 0; i < 4; ++i) {
            int idx8 = i * 256 + tid;
            int flat = idx8 * 8;
            int row = flat >> 7, col = flat & 127;
            int grow = rowbase + row;
            uint4 v = make_uint4(0, 0, 0, 0);
            if (grow < N) v = *reinterpret_cast<const uint4*>(in + (size_t)grow * 128 + col);
            *reinterpret_cast<uint4*>(&sA[row * LDK + col]) = v;
        }
    } else {
        const float* in = (const float*)in_;
#pragma unroll
        for (int i = 0; i < 8; ++i) {
            int idx4 = i * 256 + tid;
            int flat = idx4 * 4;
            int row = flat >> 7, col = flat & 127;
            int grow = rowbase + row;
            float4 v = make_float4(0.f, 0.f, 0.f, 0.f);
            if (grow < N) v = *reinterpret_cast<const float4*>(in + (size_t)grow * 128 + col);
            uint2 w;
            w.x = (unsigned int)f2bf(v.x) | ((unsigned int)f2bf(v.y) << 16);
            w.y = (unsigned int)f2bf(v.z) | ((unsigned int)f2bf(v.w) << 16);
            *reinterpret_cast<uint2*>(&sA[row * LDK + col]) = w;
        }
    }
    __syncthreads();

    int wid = tid >> 6;
    int lane = tid & 63;
    int wm = wid >> 1;
    int wn = wid & 1;
    int l15 = lane & 15;
    int lhi = lane >> 4;

    f32x4 acc[2][4] = {};
    const ushort* wb = Wt + (size_t)(wn * 64 + l15) * 128 + lhi * 8;
    const ushort* a0p = &sA[(wm * 32 + l15) * LDK + lhi * 8];
    const ushort* a1p = &sA[(wm * 32 + 16 + l15) * LDK + lhi * 8];

#pragma unroll
    for (int ks = 0; ks < 4; ++ks) {
        bf16x8 a0 = *reinterpret_cast<const bf16x8*>(a0p + ks * 32);
        bf16x8 a1 = *reinterpret_cast<const bf16x8*>(a1p + ks * 32);
#pragma unroll
        for (int ni = 0; ni < 4; ++ni) {
            bf16x8 b = *reinterpret_cast<const bf16x8*>(wb + ni * 16 * 128 + ks * 32);
            acc[0][ni] = __builtin_amdgcn_mfma_f32_16x16x32_bf16(a0, b, acc[0][ni], 0, 0, 0);
            acc[1][ni] = __builtin_amdgcn_mfma_f32_16x16x32_bf16(a1, b, acc[1][ni], 0, 0, 0);
        }
    }

#pragma unroll
    for (int ni = 0; ni < 4; ++ni) {
        int head = wn * 4 + ni;
        float alv = al[head * 16 + l15];
        float arv = ar[head * 16 + l15];
#pragma unroll
        for (int mi = 0; mi < 2; ++mi) {
#pragma unroll
            for (int reg = 0; reg < 4; ++reg) {
                int row = rowbase + wm * 32 + mi * 16 + lhi * 4 + reg;
                float v = acc[mi][ni][reg];
                float pl = v * alv;
                float pr = v * arv;
#pragma unroll
                for (int off = 8; off; off >>= 1) {
                    pl += __shfl_xor(pl, off);
                    pr += __shfl_xor(pr, off);
                }
                if (row < N) {
                    feat[(size_t)row * 128 + head * 16 + l15] = f2bf(v);
                    if (l15 == 0) {
                        el[row * 8 + head] = pl;
                        er[row * 8 + head] = pr;
                    }
                }
            }
        }
    }
}

// ---------------- per-dst-node softmax + aggregation ----------------
// One wave per node, ZERO shuffles (round-6 lesson: bpermute cost = exp cost):
//   phase 1: 64 lanes = 8 edges x 8 heads; one exp per (edge,head); result goes
//            to wave-private LDS pl[warp][lane] via one ds_write (2-way alias, free).
//   phase 2: per edge q: s via wave-uniform global load (L1 line hit, 1 request);
//            pq via broadcast ds_read pl[warp][q*8+h] (8 banks, conflict-free);
//            feat row coalesced; 2 fma. No barrier: wave-lockstep produce/consume.
//   denominator: phase-2 lsum accumulates p[e][h] identically in all 8 lanes of a
//            head-group over ALL row edges -> lsum IS the denominator. No reduce.
__global__ __launch_bounds__(256) void aggregate(const ushort* __restrict__ feat,
                                                 const float* __restrict__ el,
                                                 const float* __restrict__ er,
                                                 const int* __restrict__ rowstart,
                                                 const ushort* __restrict__ bucket,
                                                 const float* __restrict__ bias,
                                                 ushort* __restrict__ out,
                                                 int N, int do_relu) {
    __shared__ float pl[4][64];
    int w = threadIdx.x >> 6;
    int wid = (blockIdx.x * 256 + threadIdx.x) >> 6;
    int lane = threadIdx.x & 63;
    if (wid >= N) return;
    int l7 = lane & 7;    // phase-1 head
    int e8 = lane >> 3;   // phase-1 edge slot
    int h = e8;           // phase-2 head = lane>>3
    float erv = er[wid * 8 + l7];
    int beg = rowstart[wid];
    int end = rowstart[wid + 1];

    const unsigned int* fp = reinterpret_cast<const unsigned int*>(feat) + lane;

    float lsum = 0.0f, ax = 0.0f, ay = 0.0f;

    for (int base = beg; base < end; base += 8) {
        // phase 1: weight for (edge base+e8, head l7)
        int j1 = base + e8;
        bool v1 = j1 < end;
        int s1 = (int)bucket[v1 ? j1 : beg];
        float e = el[s1 * 8 + l7] + erv;
        e = (e > 0.0f) ? e : LEAKY * e;
        float pv = v1 ? __expf(e) : 0.0f;
        pl[w][lane] = pv;

        // phase 2
        int cnt = min(8, end - base);
        if (cnt == 8) {
#pragma unroll
            for (int q = 0; q < 8; ++q) {
                int s = (int)bucket[base + q];     // wave-uniform load
                float pq = pl[w][q * 8 + h];       // broadcast ds_read
                unsigned int u = fp[s * 64];       // coalesced 256B row
                lsum += pq;
                ax = fmaf(pq, __uint_as_float(u << 16), ax);
                ay = fmaf(pq, __uint_as_float(u & 0xffff0000u), ay);
            }
        } else {
            for (int q = 0; q < cnt; ++q) {        // wave-uniform tail
                int s = (int)bucket[base + q];
                float pq = pl[w][q * 8 + h];
                unsigned int u = fp[s * 64];
                lsum += pq;
                ax = fmaf(pq, __uint_as_float(u << 16), ax);
                ay = fmaf(pq, __uint_as_float(u & 0xffff0000u), ay);
            }
        }
    }

    float inv = (end > beg) ? 1.0f / lsum : 0.0f;

    int c = lane * 2;
    float2 bv = *reinterpret_cast<const float2*>(bias + c);
    float ox = fmaf(ax, inv, bv.x);
    float oy = fmaf(ay, inv, bv.y);
    if (do_relu) {
        ox = fmaxf(ox, 0.0f);
        oy = fmaxf(oy, 0.0f);
    }
    unsigned int pk = (unsigned int)f2bf(ox) | ((unsigned int)f2bf(oy) << 16);
    reinterpret_cast<unsigned int*>(out)[(size_t)wid * 64 + lane] = pk;
}

// ---------------- readout ----------------
__global__ __launch_bounds__(256) void mean_reduce(const ushort* __restrict__ h,
                                                   float* __restrict__ meanbuf, int N) {
    int c = threadIdx.x & 127;
    int rbase = blockIdx.x * 2 + (threadIdx.x >> 7);
    float s = 0.0f;
    for (int r = rbase; r < N; r += gridDim.x * 2)
        s += __uint_as_float((unsigned int)h[(size_t)r * 128 + c] << 16);
    atomicAdd(&meanbuf[c], s);
}

__global__ __launch_bounds__(64) void classifier(const float* __restrict__ meanbuf,
                                                 const float* __restrict__ Wc,
                                                 const float* __restrict__ bc,
                                                 float* __restrict__ outp, float invN) {
    int j = threadIdx.x;
    if (j < 10) {
        float s = 0.0f;
        for (int k = 0; k < 128; ++k) s += meanbuf[k] * invN * Wc[k * 10 + j];
        outp[j] = s + bc[j];
    }
}

// ---------------- launch ----------------

extern "C" void kernel_launch(void* const* d_in, const int* in_sizes, int n_in,
                              void* d_out, int out_size, void* d_ws, size_t ws_size,
                              hipStream_t stream) {
    const float* x   = (const float*)d_in[0];
    const int*   src = (const int*)d_in[1];
    const int*   dst = (const int*)d_in[2];
    const float* W1  = (const float*)d_in[3];
    const float* al1 = (const float*)d_in[4];
    const float* ar1 = (const float*)d_in[5];
    const float* b1  = (const float*)d_in[6];
    const float* W2  = (const float*)d_in[7];
    const float* al2 = (const float*)d_in[8];
    const float* ar2 = (const float*)d_in[9];
    const float* b2  = (const float*)d_in[10];
    const float* Wc  = (const float*)d_in[11];
    const float* bc  = (const float*)d_in[12];

    int N = in_sizes[0] / 128;
    int E = in_sizes[1];
    int NB = (N + (1 << BINB) - 1) >> BINB;

    size_t off = 0;
    auto alloc = [&](size_t bytes) -> void* {
        void* p = (char*)d_ws + off;
        off += (bytes + 255) & ~size_t(255);
        return p;
    };
    int*   bin_cnt    = (int*)alloc(sizeof(int) * NB);
    int*   binStart   = (int*)alloc(sizeof(int) * (NB + 1));
    int*   bin_cursor = (int*)alloc(sizeof(int) * NB);
    int*   rowstart   = (int*)alloc(sizeof(int) * (N + 1));
    unsigned int* coarse = (unsigned int*)alloc(sizeof(unsigned int) * E);
    ushort* bucket  = (ushort*)alloc(sizeof(ushort) * E);
    ushort* feat    = (ushort*)alloc(sizeof(ushort) * (size_t)N * 128);
    float* el       = (float*)alloc(sizeof(float) * N * 8);
    float* er       = (float*)alloc(sizeof(float) * N * 8);
    ushort* h1      = (ushort*)alloc(sizeof(ushort) * (size_t)N * 128);
    ushort* h2      = (ushort*)alloc(sizeof(ushort) * (size_t)N * 128);
    float* meanbuf  = (float*)alloc(sizeof(float) * 128);
    ushort* Wt1     = (ushort*)alloc(sizeof(ushort) * 128 * 128);
    ushort* Wt2     = (ushort*)alloc(sizeof(ushort) * 128 * 128);

    hipMemsetAsync(bin_cnt, 0, sizeof(int) * NB, stream);
    hipMemsetAsync(meanbuf, 0, sizeof(float) * 128, stream);

    int GB = ceil_div(E, TILE);

    bin_count<<<GB, 256, 0, stream>>>(dst, bin_cnt, E, NB);
    bin_scan<<<1, 256, 0, stream>>>(bin_cnt, binStart, bin_cursor, rowstart, NB, N, E);
    bin_scatter<<<GB, 256, 0, stream>>>(src, dst, bin_cursor, coarse, E);
    fine_csr<<<NB, 256, 0, stream>>>(coarse, binStart, rowstart, bucket, N);
    convert_w<<<128, 256, 0, stream>>>(W1, W2, Wt1, Wt2);

    // layer 1 (f32 input)
    gemm_attn_mfma<false><<<ceil_div(N, 64), 256, 0, stream>>>(x, Wt1, al1, ar1, feat, el, er, N);
    aggregate<<<ceil_div(N * 64, 256), 256, 0, stream>>>(feat, el, er, rowstart, bucket, b1, h1, N, 1);
    // layer 2 (bf16 input)
    gemm_attn_mfma<true><<<ceil_div(N, 64), 256, 0, stream>>>(h1, Wt2, al2, ar2, feat, el, er, N);
    aggregate<<<ceil_div(N * 64, 256), 256, 0, stream>>>(feat, el, er, rowstart, bucket, b2, h2, N, 0);
    // readout
    mean_reduce<<<256, 256, 0, stream>>>(h2, meanbuf, N);
    classifier<<<1, 64, 0, stream>>>(meanbuf, Wc, bc, (float*)d_out, 1.0f / (float)N);
}

// Round 8
// 240.980 us; speedup vs baseline: 1.0080x; 1.0080x over previous
//
#include <hip/hip_runtime.h>
#include <hip/hip_bf16.h>

#define LEAKY 0.2f
#define BINB 8          // 256 nodes per bin (requires N <= 65536 for u16 packing)
#define TILE 2048       // edges per block in binning kernels (391 blocks: parallelism)
#define CAP 8192        // LDS bucket-segment capacity per bin (avg ~4081)

static inline int ceil_div(int a, int b) { return (a + b - 1) / b; }

typedef __bf16 bf16x8 __attribute__((ext_vector_type(8)));
typedef float f32x4 __attribute__((ext_vector_type(4)));

// f32 -> bf16 bits, round-to-nearest-even
__device__ __forceinline__ ushort f2bf(float f) {
    unsigned int x = __float_as_uint(f);
    unsigned int r = (x + 0x7fffu + ((x >> 16) & 1u)) >> 16;
    return (ushort)r;
}

// ---------------- CSR build (two-level, coalesced writes) ----------------
// Round-4 lesson: one-pass random 4B scatter = 17x HBM write amplification.

__global__ __launch_bounds__(256) void bin_count(const int* __restrict__ dst,
                                                 int* __restrict__ bin_cnt, int E, int NB) {
    __shared__ int h[256];
    int t = threadIdx.x;
    h[t] = 0;
    __syncthreads();
    int base = blockIdx.x * TILE;
#pragma unroll
    for (int j = 0; j < TILE / 256; ++j) {
        int i = base + j * 256 + t;
        if (i < E) atomicAdd(&h[dst[i] >> BINB], 1);
    }
    __syncthreads();
    if (t < NB && h[t]) atomicAdd(&bin_cnt[t], h[t]);
}

__global__ __launch_bounds__(256) void bin_scan(const int* __restrict__ bin_cnt,
                                                int* __restrict__ binStart,
                                                int* __restrict__ bin_cursor,
                                                int* __restrict__ rowstart,
                                                int NB, int N, int E) {
    __shared__ int s[256];
    int t = threadIdx.x;
    int v = (t < NB) ? bin_cnt[t] : 0;
    s[t] = v;
    __syncthreads();
    for (int off = 1; off < 256; off <<= 1) {
        int x = (t >= off) ? s[t - off] : 0;
        __syncthreads();
        s[t] += x;
        __syncthreads();
    }
    int excl = s[t] - v;
    if (t < NB) {
        binStart[t] = excl;
        bin_cursor[t] = excl;
        if (t == NB - 1) binStart[NB] = excl + v;
    }
    if (t == 0) rowstart[N] = E;
}

__global__ __launch_bounds__(256) void bin_scatter(const int* __restrict__ src,
                                                   const int* __restrict__ dst,
                                                   int* __restrict__ bin_cursor,
                                                   unsigned int* __restrict__ coarse, int E) {
    __shared__ int hist[256], scn[256], gbase[256], lcur[256];
    __shared__ unsigned int outp[TILE];
    __shared__ int gidx[TILE];
    int t = threadIdx.x;
    hist[t] = 0;
    __syncthreads();
    int base = blockIdx.x * TILE;
    int dloc[TILE / 256];
#pragma unroll
    for (int j = 0; j < TILE / 256; ++j) {
        int i = base + j * 256 + t;
        int d = (i < E) ? dst[i] : -1;
        dloc[j] = d;
        if (d >= 0) atomicAdd(&hist[d >> BINB], 1);
    }
    __syncthreads();
    int hv = hist[t];
    scn[t] = hv;
    __syncthreads();
    for (int off = 1; off < 256; off <<= 1) {
        int x = (t >= off) ? scn[t - off] : 0;
        __syncthreads();
        scn[t] += x;
        __syncthreads();
    }
    int excl = scn[t] - hv;
    if (hv > 0) gbase[t] = atomicAdd(&bin_cursor[t], hv);
    lcur[t] = excl;
    scn[t] = excl;
    __syncthreads();
#pragma unroll
    for (int j = 0; j < TILE / 256; ++j) {
        int i = base + j * 256 + t;
        int d = dloc[j];
        if (d >= 0) {
            int b = d >> BINB;
            int pos = atomicAdd(&lcur[b], 1);
            outp[pos] = (unsigned int)src[i] | ((unsigned int)(d & ((1 << BINB) - 1)) << 16);
            gidx[pos] = gbase[b] + (pos - scn[b]);
        }
    }
    __syncthreads();
    int cnt = min(TILE, E - base);
    for (int j = t; j < cnt; j += 256) coarse[gidx[j]] = outp[j];
}

__global__ __launch_bounds__(256) void fine_csr(const unsigned int* __restrict__ coarse,
                                                const int* __restrict__ binStart,
                                                int* __restrict__ rowstart,
                                                ushort* __restrict__ bucket, int N) {
    __shared__ int hist[256], scn[256], cur[256];
    __shared__ ushort sb[CAP];
    int b = blockIdx.x, t = threadIdx.x;
    int e0 = binStart[b], e1 = binStart[b + 1];
    int cnt = e1 - e0;
    hist[t] = 0;
    __syncthreads();
    for (int j = e0 + t; j < e1; j += 256) atomicAdd(&hist[coarse[j] >> 16], 1);
    __syncthreads();
    int hv = hist[t];
    scn[t] = hv;
    __syncthreads();
    for (int off = 1; off < 256; off <<= 1) {
        int x = (t >= off) ? scn[t - off] : 0;
        __syncthreads();
        scn[t] += x;
        __syncthreads();
    }
    int excl = scn[t] - hv;
    int n = (b << BINB) + t;
    if (n < N) rowstart[n] = e0 + excl;
    cur[t] = excl;
    __syncthreads();
    bool fit = (cnt <= CAP);
    for (int j = e0 + t; j < e1; j += 256) {
        unsigned int p = coarse[j];
        int dl = p >> 16;
        int pos = atomicAdd(&cur[dl], 1);
        ushort sv = (ushort)(p & 0xffffu);
        if (fit) sb[pos] = sv;
        else bucket[e0 + pos] = sv;
    }
    __syncthreads();
    if (fit)
        for (int j = t; j < cnt; j += 256) bucket[e0 + j] = sb[j];
}

// ---------------- W convert: Wt[n][k] = bf16(W[k][n]) ----------------
__global__ __launch_bounds__(256) void convert_w(const float* __restrict__ W1,
                                                 const float* __restrict__ W2,
                                                 ushort* __restrict__ Wt1,
                                                 ushort* __restrict__ Wt2) {
    int idx = blockIdx.x * 256 + threadIdx.x;
    const float* W = (idx < 16384) ? W1 : W2;
    ushort* O = (idx < 16384) ? Wt1 : Wt2;
    int i = idx & 16383;
    int k = i >> 7, n = i & 127;
    O[n * 128 + k] = f2bf(W[i]);
}

// ---------------- MFMA GEMM + attention coefficients ----------------
// Block 64x128, 4 waves (2M x 2N). Input either f32 (layer 1) or bf16 (layer 2).
#define LDK 136
template <bool BF16IN>
__global__ __launch_bounds__(256) void gemm_attn_mfma(const void* __restrict__ in_,
                                                      const ushort* __restrict__ Wt,
                                                      const float* __restrict__ al,
                                                      const float* __restrict__ ar,
                                                      ushort* __restrict__ feat,
                                                      float* __restrict__ el,
                                                      float* __restrict__ er, int N) {
    __shared__ ushort sA[64 * LDK];
    int tid = threadIdx.x;
    int rowbase = blockIdx.x * 64;

    if (BF16IN) {
        const ushort* in = (const ushort*)in_;
#pragma unroll
        for (int i = 0; i < 4; ++i) {
            int idx8 = i * 256 + tid;
            int flat = idx8 * 8;
            int row = flat >> 7, col = flat & 127;
            int grow = rowbase + row;
            uint4 v = make_uint4(0, 0, 0, 0);
            if (grow < N) v = *reinterpret_cast<const uint4*>(in + (size_t)grow * 128 + col);
            *reinterpret_cast<uint4*>(&sA[row * LDK + col]) = v;
        }
    } else {
        const float* in = (const float*)in_;
#pragma unroll
        for (int i = 0; i < 8; ++i) {
            int idx4 = i * 256 + tid;
            int flat = idx4 * 4;
            int row = flat >> 7, col = flat & 127;
            int grow = rowbase + row;
            float4 v = make_float4(0.f, 0.f, 0.f, 0.f);
            if (grow < N) v = *reinterpret_cast<const float4*>(in + (size_t)grow * 128 + col);
            uint2 w;
            w.x = (unsigned int)f2bf(v.x) | ((unsigned int)f2bf(v.y) << 16);
            w.y = (unsigned int)f2bf(v.z) | ((unsigned int)f2bf(v.w) << 16);
            *reinterpret_cast<uint2*>(&sA[row * LDK + col]) = w;
        }
    }
    __syncthreads();

    int wid = tid >> 6;
    int lane = tid & 63;
    int wm = wid >> 1;
    int wn = wid & 1;
    int l15 = lane & 15;
    int lhi = lane >> 4;

    f32x4 acc[2][4] = {};
    const ushort* wb = Wt + (size_t)(wn * 64 + l15) * 128 + lhi * 8;
    const ushort* a0p = &sA[(wm * 32 + l15) * LDK + lhi * 8];
    const ushort* a1p = &sA[(wm * 32 + 16 + l15) * LDK + lhi * 8];

#pragma unroll
    for (int ks = 0; ks < 4; ++ks) {
        bf16x8 a0 = *reinterpret_cast<const bf16x8*>(a0p + ks * 32);
        bf16x8 a1 = *reinterpret_cast<const bf16x8*>(a1p + ks * 32);
#pragma unroll
        for (int ni = 0; ni < 4; ++ni) {
            bf16x8 b = *reinterpret_cast<const bf16x8*>(wb + ni * 16 * 128 + ks * 32);
            acc[0][ni] = __builtin_amdgcn_mfma_f32_16x16x32_bf16(a0, b, acc[0][ni], 0, 0, 0);
            acc[1][ni] = __builtin_amdgcn_mfma_f32_16x16x32_bf16(a1, b, acc[1][ni], 0, 0, 0);
        }
    }

#pragma unroll
    for (int ni = 0; ni < 4; ++ni) {
        int head = wn * 4 + ni;
        float alv = al[head * 16 + l15];
        float arv = ar[head * 16 + l15];
#pragma unroll
        for (int mi = 0; mi < 2; ++mi) {
#pragma unroll
            for (int reg = 0; reg < 4; ++reg) {
                int row = rowbase + wm * 32 + mi * 16 + lhi * 4 + reg;
                float v = acc[mi][ni][reg];
                float pl = v * alv;
                float pr = v * arv;
#pragma unroll
                for (int off = 8; off; off >>= 1) {
                    pl += __shfl_xor(pl, off);
                    pr += __shfl_xor(pr, off);
                }
                if (row < N) {
                    feat[(size_t)row * 128 + head * 16 + l15] = f2bf(v);
                    if (l15 == 0) {
                        el[row * 8 + head] = pl;
                        er[row * 8 + head] = pr;
                    }
                }
            }
        }
    }
}

// ---------------- per-dst-node softmax + aggregation ----------------
// One wave per node, ZERO shuffles (round-6 lesson: bpermute cost = exp cost):
//   phase 1: 64 lanes = 8 edges x 8 heads; one exp per (edge,head); result goes
//            to wave-private LDS pl[warp][lane] via one ds_write (2-way alias, free).
//   phase 2: per edge q: s via wave-uniform global load (L1 line hit, 1 request);
//            pq via broadcast ds_read pl[warp][q*8+h] (8 banks, conflict-free);
//            feat row coalesced; 2 fma. No barrier: wave-lockstep produce/consume.
//   denominator: phase-2 lsum accumulates p[e][h] identically in all 8 lanes of a
//            head-group over ALL row edges -> lsum IS the denominator. No reduce.
__global__ __launch_bounds__(256) void aggregate(const ushort* __restrict__ feat,
                                                 const float* __restrict__ el,
                                                 const float* __restrict__ er,
                                                 const int* __restrict__ rowstart,
                                                 const ushort* __restrict__ bucket,
                                                 const float* __restrict__ bias,
                                                 ushort* __restrict__ out,
                                                 int N, int do_relu) {
    __shared__ float pl[4][64];
    int w = threadIdx.x >> 6;
    int wid = (blockIdx.x * 256 + threadIdx.x) >> 6;
    int lane = threadIdx.x & 63;
    if (wid >= N) return;
    int l7 = lane & 7;    // phase-1 head
    int e8 = lane >> 3;   // phase-1 edge slot
    int h = e8;           // phase-2 head = lane>>3
    float erv = er[wid * 8 + l7];
    int beg = rowstart[wid];
    int end = rowstart[wid + 1];

    const unsigned int* fp = reinterpret_cast<const unsigned int*>(feat) + lane;

    float lsum = 0.0f, ax = 0.0f, ay = 0.0f;

    for (int base = beg; base < end; base += 8) {
        // phase 1: weight for (edge base+e8, head l7)
        int j1 = base + e8;
        bool v1 = j1 < end;
        int s1 = (int)bucket[v1 ? j1 : beg];
        float e = el[s1 * 8 + l7] + erv;
        e = (e > 0.0f) ? e : LEAKY * e;
        float pv = v1 ? __expf(e) : 0.0f;
        pl[w][lane] = pv;

        // phase 2
        int cnt = min(8, end - base);
        if (cnt == 8) {
#pragma unroll
            for (int q = 0; q < 8; ++q) {
                int s = (int)bucket[base + q];     // wave-uniform load
                float pq = pl[w][q * 8 + h];       // broadcast ds_read
                unsigned int u = fp[s * 64];       // coalesced 256B row
                lsum += pq;
                ax = fmaf(pq, __uint_as_float(u << 16), ax);
                ay = fmaf(pq, __uint_as_float(u & 0xffff0000u), ay);
            }
        } else {
            for (int q = 0; q < cnt; ++q) {        // wave-uniform tail
                int s = (int)bucket[base + q];
                float pq = pl[w][q * 8 + h];
                unsigned int u = fp[s * 64];
                lsum += pq;
                ax = fmaf(pq, __uint_as_float(u << 16), ax);
                ay = fmaf(pq, __uint_as_float(u & 0xffff0000u), ay);
            }
        }
    }

    float inv = (end > beg) ? 1.0f / lsum : 0.0f;

    int c = lane * 2;
    float2 bv = *reinterpret_cast<const float2*>(bias + c);
    float ox = fmaf(ax, inv, bv.x);
    float oy = fmaf(ay, inv, bv.y);
    if (do_relu) {
        ox = fmaxf(ox, 0.0f);
        oy = fmaxf(oy, 0.0f);
    }
    unsigned int pk = (unsigned int)f2bf(ox) | ((unsigned int)f2bf(oy) << 16);
    reinterpret_cast<unsigned int*>(out)[(size_t)wid * 64 + lane] = pk;
}

// ---------------- readout ----------------
__global__ __launch_bounds__(256) void mean_reduce(const ushort* __restrict__ h,
                                                   float* __restrict__ meanbuf, int N) {
    int c = threadIdx.x & 127;
    int rbase = blockIdx.x * 2 + (threadIdx.x >> 7);
    float s = 0.0f;
    for (int r = rbase; r < N; r += gridDim.x * 2)
        s += __uint_as_float((unsigned int)h[(size_t)r * 128 + c] << 16);
    atomicAdd(&meanbuf[c], s);
}

__global__ __launch_bounds__(64) void classifier(const float* __restrict__ meanbuf,
                                                 const float* __restrict__ Wc,
                                                 const float* __restrict__ bc,
                                                 float* __restrict__ outp, float invN) {
    int j = threadIdx.x;
    if (j < 10) {
        float s = 0.0f;
        for (int k = 0; k < 128; ++k) s += meanbuf[k] * invN * Wc[k * 10 + j];
        outp[j] = s + bc[j];
    }
}

// ---------------- launch ----------------

extern "C" void kernel_launch(void* const* d_in, const int* in_sizes, int n_in,
                              void* d_out, int out_size, void* d_ws, size_t ws_size,
                              hipStream_t stream) {
    const float* x   = (const float*)d_in[0];
    const int*   src = (const int*)d_in[1];
    const int*   dst = (const int*)d_in[2];
    const float* W1  = (const float*)d_in[3];
    const float* al1 = (const float*)d_in[4];
    const float* ar1 = (const float*)d_in[5];
    const float* b1  = (const float*)d_in[6];
    const float* W2  = (const float*)d_in[7];
    const float* al2 = (const float*)d_in[8];
    const float* ar2 = (const float*)d_in[9];
    const float* b2  = (const float*)d_in[10];
    const float* Wc  = (const float*)d_in[11];
    const float* bc  = (const float*)d_in[12];

    int N = in_sizes[0] / 128;
    int E = in_sizes[1];
    int NB = (N + (1 << BINB) - 1) >> BINB;

    size_t off = 0;
    auto alloc = [&](size_t bytes) -> void* {
        void* p = (char*)d_ws + off;
        off += (bytes + 255) & ~size_t(255);
        return p;
    };
    int*   bin_cnt    = (int*)alloc(sizeof(int) * NB);
    int*   binStart   = (int*)alloc(sizeof(int) * (NB + 1));
    int*   bin_cursor = (int*)alloc(sizeof(int) * NB);
    int*   rowstart   = (int*)alloc(sizeof(int) * (N + 1));
    unsigned int* coarse = (unsigned int*)alloc(sizeof(unsigned int) * E);
    ushort* bucket  = (ushort*)alloc(sizeof(ushort) * E);
    ushort* feat    = (ushort*)alloc(sizeof(ushort) * (size_t)N * 128);
    float* el       = (float*)alloc(sizeof(float) * N * 8);
    float* er       = (float*)alloc(sizeof(float) * N * 8);
    ushort* h1      = (ushort*)alloc(sizeof(ushort) * (size_t)N * 128);
    ushort* h2      = (ushort*)alloc(sizeof(ushort) * (size_t)N * 128);
    float* meanbuf  = (float*)alloc(sizeof(float) * 128);
    ushort* Wt1     = (ushort*)alloc(sizeof(ushort) * 128 * 128);
    ushort* Wt2     = (ushort*)alloc(sizeof(ushort) * 128 * 128);

    hipMemsetAsync(bin_cnt, 0, sizeof(int) * NB, stream);
    hipMemsetAsync(meanbuf, 0, sizeof(float) * 128, stream);

    int GB = ceil_div(E, TILE);

    bin_count<<<GB, 256, 0, stream>>>(dst, bin_cnt, E, NB);
    bin_scan<<<1, 256, 0, stream>>>(bin_cnt, binStart, bin_cursor, rowstart, NB, N, E);
    bin_scatter<<<GB, 256, 0, stream>>>(src, dst, bin_cursor, coarse, E);
    fine_csr<<<NB, 256, 0, stream>>>(coarse, binStart, rowstart, bucket, N);
    convert_w<<<128, 256, 0, stream>>>(W1, W2, Wt1, Wt2);

    // layer 1 (f32 input)
    gemm_attn_mfma<false><<<ceil_div(N, 64), 256, 0, stream>>>(x, Wt1, al1, ar1, feat, el, er, N);
    aggregate<<<ceil_div(N * 64, 256), 256, 0, stream>>>(feat, el, er, rowstart, bucket, b1, h1, N, 1);
    // layer 2 (bf16 input)
    gemm_attn_mfma<true><<<ceil_div(N, 64), 256, 0, stream>>>(h1, Wt2, al2, ar2, feat, el, er, N);
    aggregate<<<ceil_div(N * 64, 256), 256, 0, stream>>>(feat, el, er, rowstart, bucket, b2, h2, N, 0);
    // readout
    mean_reduce<<<256, 256, 0, stream>>>(h2, meanbuf, N);
    classifier<<<1, 64, 0, stream>>>(meanbuf, Wc, bc, (float*)d_out, 1.0f / (float)N);
}